// Round 6
// baseline (1913.148 us; speedup 1.0000x reference)
//
#include <hip/hip_runtime.h>
#include <math.h>

// ---------------------------------------------------------------------------
// bf16 MFMA with two-term hi/lo splits for fp32-grade accuracy.
// a*b ~= ah*bh + ah*bl + al*bh (lo*lo dropped). All MFMA accumulation fp32.
// Frag layouts (HW-verified): A/B: m|n = lane&15, k = (lane>>4)*8 + t;
// C/D: col = lane&15, row = (lane>>4)*4 + reg.
//
// Attention: score/PV split with P staged in global FP32 (this round).
// Rounds 3/4 with fp16 P failed absmax (8.8e-5 / 7.2e-5 vs 3.2e-5) even
// after RNE + self-consistent l; noise analysis says fp16 accounts for
// <=1e-6, so fp32-P makes the split math structurally identical to the
// fused kernel that passed at 7.6e-6 (fp32 exp numerators, fp32 l,
// postmix fp32, splitbf only at the MFMA boundary).
//   attn_score: S = QK^T, premix, exp -> store P (fp32, float4 coalesced)
//               + row sums -> IL = 1/l. Barrier-free j-loop.
//   attn_pv:    load P (prefetched across iters), *IL, postmix, splitbf ->
//               LDS, PV vs V with V prefetch chained across steps AND iters.
// P slab is chunked to fit ws_size (512 KB per (b,ib) block now).
// (Round 5 was an infra failure; identical resubmission.)
// ---------------------------------------------------------------------------

typedef short bf16x8 __attribute__((ext_vector_type(8)));
typedef float f32x4 __attribute__((ext_vector_type(4)));

__device__ __forceinline__ f32x4 mfma16(bf16x8 a, bf16x8 b, f32x4 c) {
  return __builtin_amdgcn_mfma_f32_16x16x32_bf16(a, b, c, 0, 0, 0);
}

__device__ __forceinline__ unsigned short f2bf(float f) {
  unsigned u = __float_as_uint(f);
  u = (u + 0x7fffu + ((u >> 16) & 1u)) >> 16;  // RNE
  return (unsigned short)u;
}

__device__ __forceinline__ void splitbf(float f, unsigned short& hi,
                                        unsigned short& lo) {
  hi = f2bf(f);
  float fh = __uint_as_float((unsigned)hi << 16);
  lo = f2bf(f - fh);
}

__device__ __forceinline__ f32x4 zero4() {
  f32x4 z = {0.f, 0.f, 0.f, 0.f};
  return z;
}

namespace {

constexpr int kB = 16, kN = 1024, kH = 8;

// ------------------------------------------------------------------ P0: prep
__global__ __launch_bounds__(256) void prep(
    const float* __restrict__ Wq, const float* __restrict__ Wkv,
    const float* __restrict__ Wout, unsigned short* __restrict__ WTh,
    unsigned short* __restrict__ WTl, unsigned short* __restrict__ WoTh,
    unsigned short* __restrict__ WoTl) {
  int id = blockIdx.x * 256 + threadIdx.x;  // 1,048,576 ids
  unsigned short h, l;
  if (id < 1536 * 512) {
    int n = id >> 9, k = id & 511;
    float v = (n < 512) ? Wq[(size_t)k * 512 + n]
                        : Wkv[(size_t)k * 1024 + (n - 512)];
    splitbf(v, h, l);
    WTh[id] = h; WTl[id] = l;
  } else {
    int id2 = id - 1536 * 512;
    int n = id2 >> 9, k = id2 & 511;
    splitbf(Wout[(size_t)k * 512 + n], h, l);
    WoTh[id2] = h; WoTl[id2] = l;
  }
}

// ----------------------------------------------------------------- P1: QKV
__global__ __launch_bounds__(256) void gemm_qkv(
    const float* __restrict__ X, const unsigned short* __restrict__ WTh,
    const unsigned short* __restrict__ WTl, const float* __restrict__ scale,
    unsigned short* __restrict__ Qh, unsigned short* __restrict__ Ql,
    unsigned short* __restrict__ Kh, unsigned short* __restrict__ Kl,
    unsigned short* __restrict__ Vh, unsigned short* __restrict__ Vl) {
  __shared__ unsigned short Ah[128 * 72], Al[128 * 72];
  __shared__ unsigned short Bh[128 * 72], Bl[128 * 72];
  const int tid = threadIdx.x;
  const int n0 = blockIdx.x * 128, m0 = blockIdx.y * 128;
  const int w = tid >> 6, lane = tid & 63, quad = lane >> 4, ln = lane & 15;
  const int mw = (w >> 1) * 64, nw = (w & 1) * 64;
  const int srow = tid >> 3, schk = (tid & 7) * 8;
  f32x4 acc[4][4];
#pragma unroll
  for (int i = 0; i < 4; ++i)
#pragma unroll
    for (int j = 0; j < 4; ++j) acc[i][j] = zero4();
  for (int k0 = 0; k0 < 512; k0 += 64) {
    float xa[4][8];
    uint4 bh4[4], bl4[4];
#pragma unroll
    for (int c2 = 0; c2 < 4; ++c2) {
      const float* xs = X + (size_t)(m0 + c2 * 32 + srow) * 512 + k0 + schk;
      *(float4*)&xa[c2][0] = *(const float4*)xs;
      *(float4*)&xa[c2][4] = *(const float4*)(xs + 4);
      size_t boff = (size_t)(n0 + c2 * 32 + srow) * 512 + k0 + schk;
      bh4[c2] = *(const uint4*)(WTh + boff);
      bl4[c2] = *(const uint4*)(WTl + boff);
    }
    __syncthreads();
#pragma unroll
    for (int c2 = 0; c2 < 4; ++c2) {
      unsigned short hh[8], ll[8];
#pragma unroll
      for (int e = 0; e < 8; ++e) splitbf(xa[c2][e], hh[e], ll[e]);
      uint4 ph, pl;
      ph.x = hh[0] | ((unsigned)hh[1] << 16); pl.x = ll[0] | ((unsigned)ll[1] << 16);
      ph.y = hh[2] | ((unsigned)hh[3] << 16); pl.y = ll[2] | ((unsigned)ll[3] << 16);
      ph.z = hh[4] | ((unsigned)hh[5] << 16); pl.z = ll[4] | ((unsigned)ll[5] << 16);
      ph.w = hh[6] | ((unsigned)hh[7] << 16); pl.w = ll[6] | ((unsigned)ll[7] << 16);
      *(uint4*)&Ah[(c2 * 32 + srow) * 72 + schk] = ph;
      *(uint4*)&Al[(c2 * 32 + srow) * 72 + schk] = pl;
      *(uint4*)&Bh[(c2 * 32 + srow) * 72 + schk] = bh4[c2];
      *(uint4*)&Bl[(c2 * 32 + srow) * 72 + schk] = bl4[c2];
    }
    __syncthreads();
#pragma unroll
    for (int ks = 0; ks < 2; ++ks) {
      bf16x8 afh[4], afl[4], bfh[4], bfl[4];
#pragma unroll
      for (int t = 0; t < 4; ++t) {
        int ao = (mw + t * 16 + ln) * 72 + ks * 32 + quad * 8;
        int bo = (nw + t * 16 + ln) * 72 + ks * 32 + quad * 8;
        afh[t] = *(const bf16x8*)&Ah[ao];
        afl[t] = *(const bf16x8*)&Al[ao];
        bfh[t] = *(const bf16x8*)&Bh[bo];
        bfl[t] = *(const bf16x8*)&Bl[bo];
      }
#pragma unroll
      for (int mt = 0; mt < 4; ++mt)
#pragma unroll
        for (int nt = 0; nt < 4; ++nt) {
          acc[mt][nt] = mfma16(afh[mt], bfh[nt], acc[mt][nt]);
          acc[mt][nt] = mfma16(afh[mt], bfl[nt], acc[mt][nt]);
          acc[mt][nt] = mfma16(afl[mt], bfh[nt], acc[mt][nt]);
        }
    }
  }
  const int region = n0 >> 9;
#pragma unroll
  for (int nt = 0; nt < 4; ++nt) {
    const int col = n0 + nw + nt * 16 + ln;
    const int local = col - region * 512;
    const int hh = local >> 6, d = local & 63;
    const float sc = (region == 0) ? scale[hh] : 1.f;
#pragma unroll
    for (int mt = 0; mt < 4; ++mt) {
#pragma unroll
      for (int r = 0; r < 4; ++r) {
        const int row = m0 + mw + mt * 16 + quad * 4 + r;
        const int b = row >> 10, i = row & 1023;
        unsigned short vh, vl;
        splitbf(acc[mt][nt][r] * sc, vh, vl);
        if (region == 0) {
          size_t o = (((size_t)(b * 8 + hh) * 1024 + i) << 6) + d;
          Qh[o] = vh; Ql[o] = vl;
        } else if (region == 1) {
          size_t o = (((size_t)(b * 8 + hh) * 1024 + i) << 6) + d;
          Kh[o] = vh; Kl[o] = vl;
        } else {
          size_t o = (((size_t)(b * 8 + hh) * 64 + d) << 10) + i;
          Vh[o] = vh; Vl[o] = vl;
        }
      }
    }
  }
}

// --------------------------------------------------- P2a: scores + exp + 1/l
// 256 threads = 4 waves, each wave owns a 16-j slice of a 16i x 64j tile.
// Barrier-free j-loop. P chunk layout (fp32): [chunk_blk][a][j][i16] where
// chunk_blk = blockIdx.y*gridDim.x + blockIdx.x -- each (wave, a) store is
// 64 lanes x 16B.
__global__ __launch_bounds__(256) void attn_score(
    const unsigned short* __restrict__ Qh_g, const unsigned short* __restrict__ Ql_g,
    const unsigned short* __restrict__ Kh, const unsigned short* __restrict__ Kl,
    const float* __restrict__ mix_pre, float* __restrict__ Pp,
    float* __restrict__ IL, int b0, int ib0) {
  __shared__ unsigned short Qsh[128 * 72];  // [8h*16i][72] hi
  __shared__ float mixp_s[64], dfix_s[8];
  __shared__ float lred[512];  // [4w][8a][16i]
  const int tid = threadIdx.x;
  const int b = b0 + blockIdx.y, ib = ib0 + blockIdx.x, i0 = ib * 16;
  const int w = tid >> 6, lane = tid & 63, quad = lane >> 4, ln = lane & 15;
  const int jh = w * 16;
  if (tid < 64) mixp_s[tid] = mix_pre[tid];
  if (tid < 8) {
    float s = 0.f;
#pragma unroll
    for (int h = 0; h < 8; ++h) s += mix_pre[h * 8 + tid];
    dfix_s[tid] = -1e-9f * s;  // diagonal is assigned BEFORE premix
  }
  // stage Q-hi: 8h*16i*64d shorts = 1024 uint4 chunks / 256 threads
#pragma unroll
  for (int c = 0; c < 4; ++c) {
    int v = tid + 256 * c;
    int row = v >> 3, chk = (v & 7) * 8;  // row = h*16 + i
    int h = row >> 4, ii = row & 15;
    *(uint4*)&Qsh[row * 72 + chk] =
        *(const uint4*)(Qh_g + (((size_t)(b * 8 + h) * 1024 + i0 + ii) << 6) + chk);
  }
  __syncthreads();
  const int ig0 = i0 + quad * 4;
  float l[8][4];
#pragma unroll
  for (int a = 0; a < 8; ++a)
#pragma unroll
    for (int r = 0; r < 4; ++r) l[a][r] = 0.f;
  float* Pblk = Pp + ((size_t)(blockIdx.y * gridDim.x + blockIdx.x) << 17);
  const size_t qoff = (((size_t)(b * 8) * 1024 + i0 + ln) << 6) + quad * 8;
#pragma unroll 1
  for (int j0 = 0; j0 < 1024; j0 += 64) {
    const int jj = j0 + jh + ln;  // this lane's j (B-frag n-index)
    bf16x8 kh_r[2][2], kl_r[2][2], ql_r[2][2];
#pragma unroll
    for (int ks = 0; ks < 2; ++ks) {
      size_t kro = (((size_t)(b * 8) * 1024 + jj) << 6) + ks * 32 + quad * 8;
      kh_r[0][ks] = *(const bf16x8*)(Kh + kro);
      kl_r[0][ks] = *(const bf16x8*)(Kl + kro);
      ql_r[0][ks] = *(const bf16x8*)(Ql_g + qoff + ks * 32);
    }
    f32x4 S[8];
    int cur = 0;
#pragma unroll
    for (int h = 0; h < 8; ++h) {
      const int nxt = cur ^ 1;
      if (h < 7) {
#pragma unroll
        for (int ks = 0; ks < 2; ++ks) {
          size_t kro = (((size_t)(b * 8 + h + 1) * 1024 + jj) << 6) + ks * 32 + quad * 8;
          kh_r[nxt][ks] = *(const bf16x8*)(Kh + kro);
          kl_r[nxt][ks] = *(const bf16x8*)(Kl + kro);
          ql_r[nxt][ks] = *(const bf16x8*)(Ql_g + qoff + (size_t)(h + 1) * 65536 + ks * 32);
        }
      }
      f32x4 acc = zero4();
#pragma unroll
      for (int ks = 0; ks < 2; ++ks) {
        bf16x8 ah = *(const bf16x8*)&Qsh[(h * 16 + ln) * 72 + ks * 32 + quad * 8];
        acc = mfma16(ah, kh_r[cur][ks], acc);
        acc = mfma16(ah, kl_r[cur][ks], acc);
        acc = mfma16(ql_r[cur][ks], kh_r[cur][ks], acc);
      }
      S[h] = acc;
      cur = nxt;
    }
    const int dr = jj - ig0;
    float* pj = Pblk + (size_t)jj * 16 + quad * 4;
#pragma unroll
    for (int a = 0; a < 8; ++a) {
      f32x4 sm = S[0] * mixp_s[a];
#pragma unroll
      for (int h = 1; h < 8; ++h) sm += S[h] * mixp_s[h * 8 + a];
      const float df = dfix_s[a];
      f32x4 pv;
#pragma unroll
      for (int r = 0; r < 4; ++r) {
        float vv = (r == dr) ? df : sm[r];
        pv[r] = __expf(vv);
        l[a][r] += pv[r];
      }
      *(f32x4*)(pj + (a << 14)) = pv;  // a stride = 1024*16 floats
    }
  }
  // reduce l over ln (16 lanes), then over 4 waves via LDS
#pragma unroll
  for (int off = 1; off < 16; off <<= 1)
#pragma unroll
    for (int a = 0; a < 8; ++a)
#pragma unroll
      for (int r = 0; r < 4; ++r) l[a][r] += __shfl_xor(l[a][r], off);
  if (ln == 0) {
#pragma unroll
    for (int a = 0; a < 8; ++a)
#pragma unroll
      for (int r = 0; r < 4; ++r)
        lred[(w * 8 + a) * 16 + quad * 4 + r] = l[a][r];
  }
  __syncthreads();
  if (tid < 128) {
    int a = tid >> 4, i = tid & 15;
    float s = lred[a * 16 + i] + lred[(8 + a) * 16 + i] +
              lred[(16 + a) * 16 + i] + lred[(24 + a) * 16 + i];
    IL[(((size_t)b * 8 + a) << 10) + i0 + i] = 1.f / s;
  }
}

// ------------------------------------------------------- P2b: postmix + PV
// 256 threads = 4 waves. Stage role: wave w postmixes the 16-j slice jh=w*16
// of a 16i x 64j W tile into LDS. Compute role: wave w owns output heads
// c in {2w, 2w+1}. P loads for iter t+1 are issued during PV of iter t and
// scaled after the trailing barrier; V frags are double-buffered across
// the 4 (cc,ks) steps and chained across iterations.
__global__ __launch_bounds__(256) void attn_pv(
    const float* __restrict__ Pp, const float* __restrict__ IL,
    const unsigned short* __restrict__ Vh, const unsigned short* __restrict__ Vl,
    const float* __restrict__ mix_post, float* __restrict__ OA,
    int b0, int ib0) {
  __shared__ unsigned short Wsh[128 * 72], Wsl[128 * 72];  // [8c*16i][72]
  __shared__ float mixq_s[64];
  __shared__ float Ils[8][16];
  const int tid = threadIdx.x;
  const int b = b0 + blockIdx.y, ib = ib0 + blockIdx.x, i0 = ib * 16;
  const int w = tid >> 6, lane = tid & 63, quad = lane >> 4, ln = lane & 15;
  const int jh = w * 16;
  if (tid < 64) mixq_s[tid] = mix_post[tid];
  if (tid < 128) {
    int a = tid >> 4, i = tid & 15;
    Ils[a][i] = IL[(((size_t)b * 8 + a) << 10) + i0 + i];
  }
  __syncthreads();
  const float* Pblk = Pp + ((size_t)(blockIdx.y * gridDim.x + blockIdx.x) << 17);
  const int cw = w * 2;
  f32x4 O[2][4];
#pragma unroll
  for (int cc = 0; cc < 2; ++cc)
#pragma unroll
    for (int nt = 0; nt < 4; ++nt) O[cc][nt] = zero4();
  // prologue: load + scale P for t=0; V frags for step 0
  f32x4 praw[8];
  {
    const float* pj = Pblk + (size_t)(jh + ln) * 16 + quad * 4;
#pragma unroll
    for (int a = 0; a < 8; ++a) praw[a] = *(const f32x4*)(pj + (a << 14));
  }
  f32x4 pa[8];
#pragma unroll
  for (int a = 0; a < 8; ++a) pa[a] = praw[a] * *(const f32x4*)&Ils[a][quad * 4];
  bf16x8 vbh[2][4], vbl[2][4];
#pragma unroll
  for (int nt = 0; nt < 4; ++nt) {
    size_t vo = (((size_t)(b * 8 + cw) * 64 + nt * 16 + ln) << 10) + quad * 8;
    vbh[0][nt] = *(const bf16x8*)(Vh + vo);
    vbl[0][nt] = *(const bf16x8*)(Vl + vo);
  }
#pragma unroll 1
  for (int t = 0; t < 16; ++t) {
    const int j0 = t * 64;
    // postmix -> Ws (hi/lo bf16)
#pragma unroll
    for (int c = 0; c < 8; ++c) {
      f32x4 wv = pa[0] * mixq_s[c];
#pragma unroll
      for (int a = 1; a < 8; ++a) wv += pa[a] * mixq_s[a * 8 + c];
#pragma unroll
      for (int r = 0; r < 4; ++r) {
        unsigned short vhh, vll;
        splitbf(wv[r], vhh, vll);
        int o = (c * 16 + quad * 4 + r) * 72 + jh + ln;
        Wsh[o] = vhh; Wsl[o] = vll;
      }
    }
    __syncthreads();
    // PV: 4 steps (cc,ks); V prefetch chained; P for t+1 issued at step 0
#pragma unroll
    for (int s = 0; s < 4; ++s) {
      const int cc = s >> 1, ks = s & 1;
      const int c = cw + cc;
      const int vcur = s & 1, vnxt = vcur ^ 1;
      if (s < 3) {
        const int cc2 = (s + 1) >> 1, ks2 = (s + 1) & 1;
#pragma unroll
        for (int nt = 0; nt < 4; ++nt) {
          size_t vo = (((size_t)(b * 8 + cw + cc2) * 64 + nt * 16 + ln) << 10) +
                      j0 + ks2 * 32 + quad * 8;
          vbh[vnxt][nt] = *(const bf16x8*)(Vh + vo);
          vbl[vnxt][nt] = *(const bf16x8*)(Vl + vo);
        }
      } else if (t < 15) {  // chain: next iter's step 0
#pragma unroll
        for (int nt = 0; nt < 4; ++nt) {
          size_t vo = (((size_t)(b * 8 + cw) * 64 + nt * 16 + ln) << 10) +
                      j0 + 64 + quad * 8;
          vbh[vnxt][nt] = *(const bf16x8*)(Vh + vo);
          vbl[vnxt][nt] = *(const bf16x8*)(Vl + vo);
        }
      }
      if (s == 0 && t < 15) {
        const float* pj = Pblk + (size_t)(j0 + 64 + jh + ln) * 16 + quad * 4;
#pragma unroll
        for (int a = 0; a < 8; ++a) praw[a] = *(const f32x4*)(pj + (a << 14));
      }
      bf16x8 a_h = *(const bf16x8*)&Wsh[(c * 16 + ln) * 72 + ks * 32 + quad * 8];
      bf16x8 a_l = *(const bf16x8*)&Wsl[(c * 16 + ln) * 72 + ks * 32 + quad * 8];
#pragma unroll
      for (int nt = 0; nt < 4; ++nt) {
        O[cc][nt] = mfma16(a_h, vbh[vcur][nt], O[cc][nt]);
        O[cc][nt] = mfma16(a_h, vbl[vcur][nt], O[cc][nt]);
        O[cc][nt] = mfma16(a_l, vbh[vcur][nt], O[cc][nt]);
      }
    }
    __syncthreads();
    if (t < 15) {
#pragma unroll
      for (int a = 0; a < 8; ++a)
        pa[a] = praw[a] * *(const f32x4*)&Ils[a][quad * 4];
    }
  }
#pragma unroll
  for (int cc = 0; cc < 2; ++cc)
#pragma unroll
    for (int nt = 0; nt < 4; ++nt)
#pragma unroll
      for (int r = 0; r < 4; ++r) {
        const int i = i0 + quad * 4 + r;
        const int col = (cw + cc) * 64 + nt * 16 + ln;
        OA[((size_t)(b * 1024 + i) << 9) + col] = O[cc][nt][r];
      }
}

// ------------------------------------------------------------- P4: out-proj
__global__ __launch_bounds__(256) void gemm_out(
    const float* __restrict__ A, const unsigned short* __restrict__ BTh,
    const unsigned short* __restrict__ BTl, const float* __restrict__ bias,
    float* __restrict__ Out) {
  __shared__ unsigned short Ah[128 * 72], Al[128 * 72];
  __shared__ unsigned short Bh[128 * 72], Bl[128 * 72];
  const int tid = threadIdx.x;
  const int n0 = blockIdx.x * 128, m0 = blockIdx.y * 128;
  const int w = tid >> 6, lane = tid & 63, quad = lane >> 4, ln = lane & 15;
  const int mw = (w >> 1) * 64, nw = (w & 1) * 64;
  const int srow = tid >> 3, schk = (tid & 7) * 8;
  f32x4 acc[4][4];
#pragma unroll
  for (int i = 0; i < 4; ++i)
#pragma unroll
    for (int j = 0; j < 4; ++j) acc[i][j] = zero4();
  for (int k0 = 0; k0 < 512; k0 += 64) {
    float xa[4][8];
    uint4 bh4[4], bl4[4];
#pragma unroll
    for (int c2 = 0; c2 < 4; ++c2) {
      const float* xs = A + (size_t)(m0 + c2 * 32 + srow) * 512 + k0 + schk;
      *(float4*)&xa[c2][0] = *(const float4*)xs;
      *(float4*)&xa[c2][4] = *(const float4*)(xs + 4);
      size_t boff = (size_t)(n0 + c2 * 32 + srow) * 512 + k0 + schk;
      bh4[c2] = *(const uint4*)(BTh + boff);
      bl4[c2] = *(const uint4*)(BTl + boff);
    }
    __syncthreads();
#pragma unroll
    for (int c2 = 0; c2 < 4; ++c2) {
      unsigned short hh[8], ll[8];
#pragma unroll
      for (int e = 0; e < 8; ++e) splitbf(xa[c2][e], hh[e], ll[e]);
      uint4 ph, pl;
      ph.x = hh[0] | ((unsigned)hh[1] << 16); pl.x = ll[0] | ((unsigned)ll[1] << 16);
      ph.y = hh[2] | ((unsigned)hh[3] << 16); pl.y = ll[2] | ((unsigned)ll[3] << 16);
      ph.z = hh[4] | ((unsigned)hh[5] << 16); pl.z = ll[4] | ((unsigned)ll[5] << 16);
      ph.w = hh[6] | ((unsigned)hh[7] << 16); pl.w = ll[6] | ((unsigned)ll[7] << 16);
      *(uint4*)&Ah[(c2 * 32 + srow) * 72 + schk] = ph;
      *(uint4*)&Al[(c2 * 32 + srow) * 72 + schk] = pl;
      *(uint4*)&Bh[(c2 * 32 + srow) * 72 + schk] = bh4[c2];
      *(uint4*)&Bl[(c2 * 32 + srow) * 72 + schk] = bl4[c2];
    }
    __syncthreads();
#pragma unroll
    for (int ks = 0; ks < 2; ++ks) {
      bf16x8 afh[4], afl[4], bfh[4], bfl[4];
#pragma unroll
      for (int t = 0; t < 4; ++t) {
        int ao = (mw + t * 16 + ln) * 72 + ks * 32 + quad * 8;
        int bo = (nw + t * 16 + ln) * 72 + ks * 32 + quad * 8;
        afh[t] = *(const bf16x8*)&Ah[ao];
        afl[t] = *(const bf16x8*)&Al[ao];
        bfh[t] = *(const bf16x8*)&Bh[bo];
        bfl[t] = *(const bf16x8*)&Bl[bo];
      }
#pragma unroll
      for (int mt = 0; mt < 4; ++mt)
#pragma unroll
        for (int nt = 0; nt < 4; ++nt) {
          acc[mt][nt] = mfma16(afh[mt], bfh[nt], acc[mt][nt]);
          acc[mt][nt] = mfma16(afh[mt], bfl[nt], acc[mt][nt]);
          acc[mt][nt] = mfma16(afl[mt], bfh[nt], acc[mt][nt]);
        }
    }
  }
#pragma unroll
  for (int nt = 0; nt < 4; ++nt) {
    const int col = n0 + nw + nt * 16 + ln;
    const float bcol = bias[col];
#pragma unroll
    for (int mt = 0; mt < 4; ++mt) {
#pragma unroll
      for (int r = 0; r < 4; ++r) {
        const int row = m0 + mw + mt * 16 + quad * 4 + r;
        Out[(size_t)row * 512 + col] = acc[mt][nt][r] + bcol;
      }
    }
  }
}

}  // namespace

extern "C" void kernel_launch(void* const* d_in, const int* in_sizes, int n_in,
                              void* d_out, int out_size, void* d_ws, size_t ws_size,
                              hipStream_t stream) {
  const float* x        = (const float*)d_in[0];
  const float* Wq       = (const float*)d_in[1];
  const float* Wkv      = (const float*)d_in[2];
  const float* scale    = (const float*)d_in[3];
  const float* mix_pre  = (const float*)d_in[4];
  const float* mix_post = (const float*)d_in[5];
  const float* Wout     = (const float*)d_in[6];
  const float* bout     = (const float*)d_in[7];
  float* out = (float*)d_out;

  char* p = (char*)d_ws;
  const size_t qsz = (size_t)kB * kH * kN * 64;  // 8,388,608 elems
  unsigned short* WTh  = (unsigned short*)p; p += (size_t)1536 * 512 * 2;
  unsigned short* WTl  = (unsigned short*)p; p += (size_t)1536 * 512 * 2;
  unsigned short* WoTh = (unsigned short*)p; p += (size_t)512 * 512 * 2;
  unsigned short* WoTl = (unsigned short*)p; p += (size_t)512 * 512 * 2;
  unsigned short* Qh   = (unsigned short*)p; p += qsz * 2;
  unsigned short* Ql   = (unsigned short*)p; p += qsz * 2;
  unsigned short* Kh   = (unsigned short*)p; p += qsz * 2;
  unsigned short* Kl   = (unsigned short*)p; p += qsz * 2;
  unsigned short* Vh   = (unsigned short*)p; p += qsz * 2;
  unsigned short* Vl   = (unsigned short*)p; p += qsz * 2;
  float* OA = (float*)p; p += (size_t)kB * kN * 512 * 4;  // fp32, 33.5 MB
  float* ILp = (float*)p; p += (size_t)131072 * 4;        // 0.5 MB
  float* Pp = (float*)p;                                  // chunked P slab
  // fixed footprint up to here: ~138.9 MB

  const size_t fixed = (size_t)(p - (char*)d_ws);
  const size_t avail = (ws_size > fixed) ? (ws_size - fixed) : 0;
  const size_t per_ib = (size_t)131072 * 4;  // 512 KB per (b, ib) P block
  const size_t per_b = per_ib * 64;          // 32 MB per batch
  int cb, cib;
  if (avail >= per_b) {
    cb = (int)(avail / per_b);
    if (cb > 16) cb = 16;
    cib = 64;
  } else {
    cb = 1;
    cib = (int)(avail / per_ib);
    if (cib > 64) cib = 64;
    if (cib < 1) cib = 1;  // ws_size < fixed+512KB would still fault; assumed not
  }

  prep<<<4096, 256, 0, stream>>>(Wq, Wkv, Wout, WTh, WTl, WoTh, WoTl);
  gemm_qkv<<<dim3(12, 128), 256, 0, stream>>>(x, WTh, WTl, scale,
                                              Qh, Ql, Kh, Kl, Vh, Vl);
  for (int b0 = 0; b0 < 16; b0 += cb) {
    const int nb = (b0 + cb <= 16) ? cb : (16 - b0);
    for (int ib0 = 0; ib0 < 64; ib0 += cib) {
      const int nib = (ib0 + cib <= 64) ? cib : (64 - ib0);
      attn_score<<<dim3(nib, nb), 256, 0, stream>>>(Qh, Ql, Kh, Kl, mix_pre,
                                                    Pp, ILp, b0, ib0);
      attn_pv<<<dim3(nib, nb), 256, 0, stream>>>(Pp, ILp, Vh, Vl, mix_post,
                                                 OA, b0, ib0);
    }
  }
  gemm_out<<<dim3(4, 128), 256, 0, stream>>>(OA, WoTh, WoTl, bout, out);
}

// Round 7
// 1579.280 us; speedup vs baseline: 1.2114x; 1.2114x over previous
//
#include <hip/hip_runtime.h>
#include <math.h>

// ---------------------------------------------------------------------------
// bf16 MFMA with two-term hi/lo splits for fp32-grade accuracy.
// a*b ~= ah*bh + ah*bl + al*bh (lo*lo dropped). All MFMA accumulation fp32.
// Frag layouts (HW-verified): A/B: m|n = lane&15, k = (lane>>4)*8 + t;
// C/D: col = lane&15, row = (lane>>4)*4 + reg.
//
// Attention (this round): NO P materialization. Round-6 evidence: fp32-P
// passed (7.6e-6) but ws-chunked launches ran ~192-block grids (<1 blk/CU)
// and P cost ~1 GB traffic -> attn total WORSE than fused. fp16-P is
// mathematically dead (noise propagates to ~5e-5 at output > 3.2e-5 thr).
// New structure = two full-grid kernels (1024 blocks, 256 thr):
//   attn_lsum: QK^T + premix + exp -> row sums only -> IL = 1/l.
//              Barrier-free j-loop (proven attn_score structure).
//   attn_pv:   recompute S identically, p = exp(s)*IL, postmix -> W
//              hi/lo in LDS per 64-j tile, PV vs V with chained V
//              prefetch (proven attn_pv step structure). 2 barriers/tile.
// Recompute cost == old fused kernel's sweep 2; parallelism is 2x better
// (256 thr, 64-j tiles) and there is no P traffic / chunking.
// Workspace back to fixed ~139 MB (known to fit).
// ---------------------------------------------------------------------------

typedef short bf16x8 __attribute__((ext_vector_type(8)));
typedef float f32x4 __attribute__((ext_vector_type(4)));

__device__ __forceinline__ f32x4 mfma16(bf16x8 a, bf16x8 b, f32x4 c) {
  return __builtin_amdgcn_mfma_f32_16x16x32_bf16(a, b, c, 0, 0, 0);
}

__device__ __forceinline__ unsigned short f2bf(float f) {
  unsigned u = __float_as_uint(f);
  u = (u + 0x7fffu + ((u >> 16) & 1u)) >> 16;  // RNE
  return (unsigned short)u;
}

__device__ __forceinline__ void splitbf(float f, unsigned short& hi,
                                        unsigned short& lo) {
  hi = f2bf(f);
  float fh = __uint_as_float((unsigned)hi << 16);
  lo = f2bf(f - fh);
}

__device__ __forceinline__ f32x4 zero4() {
  f32x4 z = {0.f, 0.f, 0.f, 0.f};
  return z;
}

namespace {

constexpr int kB = 16, kN = 1024, kH = 8;

// ------------------------------------------------------------------ P0: prep
__global__ __launch_bounds__(256) void prep(
    const float* __restrict__ Wq, const float* __restrict__ Wkv,
    const float* __restrict__ Wout, unsigned short* __restrict__ WTh,
    unsigned short* __restrict__ WTl, unsigned short* __restrict__ WoTh,
    unsigned short* __restrict__ WoTl) {
  int id = blockIdx.x * 256 + threadIdx.x;  // 1,048,576 ids
  unsigned short h, l;
  if (id < 1536 * 512) {
    int n = id >> 9, k = id & 511;
    float v = (n < 512) ? Wq[(size_t)k * 512 + n]
                        : Wkv[(size_t)k * 1024 + (n - 512)];
    splitbf(v, h, l);
    WTh[id] = h; WTl[id] = l;
  } else {
    int id2 = id - 1536 * 512;
    int n = id2 >> 9, k = id2 & 511;
    splitbf(Wout[(size_t)k * 512 + n], h, l);
    WoTh[id2] = h; WoTl[id2] = l;
  }
}

// ----------------------------------------------------------------- P1: QKV
__global__ __launch_bounds__(256) void gemm_qkv(
    const float* __restrict__ X, const unsigned short* __restrict__ WTh,
    const unsigned short* __restrict__ WTl, const float* __restrict__ scale,
    unsigned short* __restrict__ Qh, unsigned short* __restrict__ Ql,
    unsigned short* __restrict__ Kh, unsigned short* __restrict__ Kl,
    unsigned short* __restrict__ Vh, unsigned short* __restrict__ Vl) {
  __shared__ unsigned short Ah[128 * 72], Al[128 * 72];
  __shared__ unsigned short Bh[128 * 72], Bl[128 * 72];
  const int tid = threadIdx.x;
  const int n0 = blockIdx.x * 128, m0 = blockIdx.y * 128;
  const int w = tid >> 6, lane = tid & 63, quad = lane >> 4, ln = lane & 15;
  const int mw = (w >> 1) * 64, nw = (w & 1) * 64;
  const int srow = tid >> 3, schk = (tid & 7) * 8;
  f32x4 acc[4][4];
#pragma unroll
  for (int i = 0; i < 4; ++i)
#pragma unroll
    for (int j = 0; j < 4; ++j) acc[i][j] = zero4();
  for (int k0 = 0; k0 < 512; k0 += 64) {
    float xa[4][8];
    uint4 bh4[4], bl4[4];
#pragma unroll
    for (int c2 = 0; c2 < 4; ++c2) {
      const float* xs = X + (size_t)(m0 + c2 * 32 + srow) * 512 + k0 + schk;
      *(float4*)&xa[c2][0] = *(const float4*)xs;
      *(float4*)&xa[c2][4] = *(const float4*)(xs + 4);
      size_t boff = (size_t)(n0 + c2 * 32 + srow) * 512 + k0 + schk;
      bh4[c2] = *(const uint4*)(WTh + boff);
      bl4[c2] = *(const uint4*)(WTl + boff);
    }
    __syncthreads();
#pragma unroll
    for (int c2 = 0; c2 < 4; ++c2) {
      unsigned short hh[8], ll[8];
#pragma unroll
      for (int e = 0; e < 8; ++e) splitbf(xa[c2][e], hh[e], ll[e]);
      uint4 ph, pl;
      ph.x = hh[0] | ((unsigned)hh[1] << 16); pl.x = ll[0] | ((unsigned)ll[1] << 16);
      ph.y = hh[2] | ((unsigned)hh[3] << 16); pl.y = ll[2] | ((unsigned)ll[3] << 16);
      ph.z = hh[4] | ((unsigned)hh[5] << 16); pl.z = ll[4] | ((unsigned)ll[5] << 16);
      ph.w = hh[6] | ((unsigned)hh[7] << 16); pl.w = ll[6] | ((unsigned)ll[7] << 16);
      *(uint4*)&Ah[(c2 * 32 + srow) * 72 + schk] = ph;
      *(uint4*)&Al[(c2 * 32 + srow) * 72 + schk] = pl;
      *(uint4*)&Bh[(c2 * 32 + srow) * 72 + schk] = bh4[c2];
      *(uint4*)&Bl[(c2 * 32 + srow) * 72 + schk] = bl4[c2];
    }
    __syncthreads();
#pragma unroll
    for (int ks = 0; ks < 2; ++ks) {
      bf16x8 afh[4], afl[4], bfh[4], bfl[4];
#pragma unroll
      for (int t = 0; t < 4; ++t) {
        int ao = (mw + t * 16 + ln) * 72 + ks * 32 + quad * 8;
        int bo = (nw + t * 16 + ln) * 72 + ks * 32 + quad * 8;
        afh[t] = *(const bf16x8*)&Ah[ao];
        afl[t] = *(const bf16x8*)&Al[ao];
        bfh[t] = *(const bf16x8*)&Bh[bo];
        bfl[t] = *(const bf16x8*)&Bl[bo];
      }
#pragma unroll
      for (int mt = 0; mt < 4; ++mt)
#pragma unroll
        for (int nt = 0; nt < 4; ++nt) {
          acc[mt][nt] = mfma16(afh[mt], bfh[nt], acc[mt][nt]);
          acc[mt][nt] = mfma16(afh[mt], bfl[nt], acc[mt][nt]);
          acc[mt][nt] = mfma16(afl[mt], bfh[nt], acc[mt][nt]);
        }
    }
  }
  const int region = n0 >> 9;
#pragma unroll
  for (int nt = 0; nt < 4; ++nt) {
    const int col = n0 + nw + nt * 16 + ln;
    const int local = col - region * 512;
    const int hh = local >> 6, d = local & 63;
    const float sc = (region == 0) ? scale[hh] : 1.f;
#pragma unroll
    for (int mt = 0; mt < 4; ++mt) {
#pragma unroll
      for (int r = 0; r < 4; ++r) {
        const int row = m0 + mw + mt * 16 + quad * 4 + r;
        const int b = row >> 10, i = row & 1023;
        unsigned short vh, vl;
        splitbf(acc[mt][nt][r] * sc, vh, vl);
        if (region == 0) {
          size_t o = (((size_t)(b * 8 + hh) * 1024 + i) << 6) + d;
          Qh[o] = vh; Ql[o] = vl;
        } else if (region == 1) {
          size_t o = (((size_t)(b * 8 + hh) * 1024 + i) << 6) + d;
          Kh[o] = vh; Kl[o] = vl;
        } else {
          size_t o = (((size_t)(b * 8 + hh) * 64 + d) << 10) + i;
          Vh[o] = vh; Vl[o] = vl;
        }
      }
    }
  }
}

// ------------------------------------------------------ P2a: l sums -> IL
// 256 threads = 4 waves, each wave owns a 16-j slice of a 16i x 64j tile.
// Barrier-free j-loop (proven attn_score structure, P stores removed).
__global__ __launch_bounds__(256) void attn_lsum(
    const unsigned short* __restrict__ Qh_g, const unsigned short* __restrict__ Ql_g,
    const unsigned short* __restrict__ Kh, const unsigned short* __restrict__ Kl,
    const float* __restrict__ mix_pre, float* __restrict__ IL) {
  __shared__ unsigned short Qsh[128 * 72];  // [8h*16i][72] hi
  __shared__ float mixp_s[64], dfix_s[8];
  __shared__ float lred[512];  // [4w][8a][16i]
  const int tid = threadIdx.x;
  const int b = blockIdx.y, ib = blockIdx.x, i0 = ib * 16;
  const int w = tid >> 6, lane = tid & 63, quad = lane >> 4, ln = lane & 15;
  const int jh = w * 16;
  if (tid < 64) mixp_s[tid] = mix_pre[tid];
  if (tid < 8) {
    float s = 0.f;
#pragma unroll
    for (int h = 0; h < 8; ++h) s += mix_pre[h * 8 + tid];
    dfix_s[tid] = -1e-9f * s;  // diagonal is assigned BEFORE premix
  }
  // stage Q-hi: 8h*16i*64d shorts = 1024 uint4 chunks / 256 threads
#pragma unroll
  for (int c = 0; c < 4; ++c) {
    int v = tid + 256 * c;
    int row = v >> 3, chk = (v & 7) * 8;  // row = h*16 + i
    int h = row >> 4, ii = row & 15;
    *(uint4*)&Qsh[row * 72 + chk] =
        *(const uint4*)(Qh_g + (((size_t)(b * 8 + h) * 1024 + i0 + ii) << 6) + chk);
  }
  __syncthreads();
  const int ig0 = i0 + quad * 4;
  float l[8][4];
#pragma unroll
  for (int a = 0; a < 8; ++a)
#pragma unroll
    for (int r = 0; r < 4; ++r) l[a][r] = 0.f;
  const size_t qoff = (((size_t)(b * 8) * 1024 + i0 + ln) << 6) + quad * 8;
#pragma unroll 1
  for (int j0 = 0; j0 < 1024; j0 += 64) {
    const int jj = j0 + jh + ln;  // this lane's j (B-frag n-index)
    bf16x8 kh_r[2][2], kl_r[2][2], ql_r[2][2];
#pragma unroll
    for (int ks = 0; ks < 2; ++ks) {
      size_t kro = (((size_t)(b * 8) * 1024 + jj) << 6) + ks * 32 + quad * 8;
      kh_r[0][ks] = *(const bf16x8*)(Kh + kro);
      kl_r[0][ks] = *(const bf16x8*)(Kl + kro);
      ql_r[0][ks] = *(const bf16x8*)(Ql_g + qoff + ks * 32);
    }
    f32x4 S[8];
    int cur = 0;
#pragma unroll
    for (int h = 0; h < 8; ++h) {
      const int nxt = cur ^ 1;
      if (h < 7) {
#pragma unroll
        for (int ks = 0; ks < 2; ++ks) {
          size_t kro = (((size_t)(b * 8 + h + 1) * 1024 + jj) << 6) + ks * 32 + quad * 8;
          kh_r[nxt][ks] = *(const bf16x8*)(Kh + kro);
          kl_r[nxt][ks] = *(const bf16x8*)(Kl + kro);
          ql_r[nxt][ks] = *(const bf16x8*)(Ql_g + qoff + (size_t)(h + 1) * 65536 + ks * 32);
        }
      }
      f32x4 acc = zero4();
#pragma unroll
      for (int ks = 0; ks < 2; ++ks) {
        bf16x8 ah = *(const bf16x8*)&Qsh[(h * 16 + ln) * 72 + ks * 32 + quad * 8];
        acc = mfma16(ah, kh_r[cur][ks], acc);
        acc = mfma16(ah, kl_r[cur][ks], acc);
        acc = mfma16(ql_r[cur][ks], kh_r[cur][ks], acc);
      }
      S[h] = acc;
      cur = nxt;
    }
    const int dr = jj - ig0;
#pragma unroll
    for (int a = 0; a < 8; ++a) {
      f32x4 sm = S[0] * mixp_s[a];
#pragma unroll
      for (int h = 1; h < 8; ++h) sm += S[h] * mixp_s[h * 8 + a];
      const float df = dfix_s[a];
#pragma unroll
      for (int r = 0; r < 4; ++r) {
        float vv = (r == dr) ? df : sm[r];
        l[a][r] += __expf(vv);
      }
    }
  }
  // reduce l over ln (16 lanes), then over 4 waves via LDS
#pragma unroll
  for (int off = 1; off < 16; off <<= 1)
#pragma unroll
    for (int a = 0; a < 8; ++a)
#pragma unroll
      for (int r = 0; r < 4; ++r) l[a][r] += __shfl_xor(l[a][r], off);
  if (ln == 0) {
#pragma unroll
    for (int a = 0; a < 8; ++a)
#pragma unroll
      for (int r = 0; r < 4; ++r)
        lred[(w * 8 + a) * 16 + quad * 4 + r] = l[a][r];
  }
  __syncthreads();
  if (tid < 128) {
    int a = tid >> 4, i = tid & 15;
    float s = lred[a * 16 + i] + lred[(8 + a) * 16 + i] +
              lred[(16 + a) * 16 + i] + lred[(24 + a) * 16 + i];
    IL[(((size_t)b * 8 + a) << 10) + i0 + i] = 1.f / s;
  }
}

// --------------------------------------- P2b: recompute S, postmix, PV
// 256 threads = 4 waves. S phase: wave w computes S for its 16-j slice of
// a 16i x 64j tile (identical math to attn_lsum), p = exp(s)*IL, postmix
// -> W hi/lo in LDS. PV phase: wave w owns output heads c in {2w, 2w+1},
// 4 (cc,ks) steps over the 64-j tile, V frags double-buffered across steps
// and chained across tiles. 2 barriers per tile.
__global__ __launch_bounds__(256) void attn_pv(
    const unsigned short* __restrict__ Qh_g, const unsigned short* __restrict__ Ql_g,
    const unsigned short* __restrict__ Kh, const unsigned short* __restrict__ Kl,
    const unsigned short* __restrict__ Vh, const unsigned short* __restrict__ Vl,
    const float* __restrict__ IL, const float* __restrict__ mix_pre,
    const float* __restrict__ mix_post, float* __restrict__ OA) {
  __shared__ unsigned short Qsh[128 * 72];                 // [8h*16i][72] hi
  __shared__ unsigned short Wsh[128 * 72], Wsl[128 * 72];  // [8c*16i][72]
  __shared__ float mixp_s[64], mixq_s[64], dfix_s[8];
  __shared__ float Ils[8][16];
  const int tid = threadIdx.x;
  const int b = blockIdx.y, ib = blockIdx.x, i0 = ib * 16;
  const int w = tid >> 6, lane = tid & 63, quad = lane >> 4, ln = lane & 15;
  const int jh = w * 16;
  if (tid < 64) { mixp_s[tid] = mix_pre[tid]; mixq_s[tid] = mix_post[tid]; }
  if (tid < 8) {
    float s = 0.f;
#pragma unroll
    for (int h = 0; h < 8; ++h) s += mix_pre[h * 8 + tid];
    dfix_s[tid] = -1e-9f * s;
  }
  if (tid >= 128) {
    int a = (tid - 128) >> 4, i = tid & 15;
    Ils[a][i] = IL[(((size_t)b * 8 + a) << 10) + i0 + i];
  }
  // stage Q-hi
#pragma unroll
  for (int c = 0; c < 4; ++c) {
    int v = tid + 256 * c;
    int row = v >> 3, chk = (v & 7) * 8;
    int h = row >> 4, ii = row & 15;
    *(uint4*)&Qsh[row * 72 + chk] =
        *(const uint4*)(Qh_g + (((size_t)(b * 8 + h) * 1024 + i0 + ii) << 6) + chk);
  }
  __syncthreads();
  const int ig0 = i0 + quad * 4;
  const int cw = w * 2;
  const size_t qoff = (((size_t)(b * 8) * 1024 + i0 + ln) << 6) + quad * 8;
  f32x4 O[2][4];
#pragma unroll
  for (int cc = 0; cc < 2; ++cc)
#pragma unroll
    for (int nt = 0; nt < 4; ++nt) O[cc][nt] = zero4();
  // prologue: V frags for tile 0, step 0 (c=cw, ks=0)
  bf16x8 vbh[2][4], vbl[2][4];
#pragma unroll
  for (int nt = 0; nt < 4; ++nt) {
    size_t vo = (((size_t)(b * 8 + cw) * 64 + nt * 16 + ln) << 10) + quad * 8;
    vbh[0][nt] = *(const bf16x8*)(Vh + vo);
    vbl[0][nt] = *(const bf16x8*)(Vl + vo);
  }
#pragma unroll 1
  for (int j0 = 0; j0 < 1024; j0 += 64) {
    const int jj = j0 + jh + ln;
    // ---- S phase (identical to attn_lsum) ----
    bf16x8 kh_r[2][2], kl_r[2][2], ql_r[2][2];
#pragma unroll
    for (int ks = 0; ks < 2; ++ks) {
      size_t kro = (((size_t)(b * 8) * 1024 + jj) << 6) + ks * 32 + quad * 8;
      kh_r[0][ks] = *(const bf16x8*)(Kh + kro);
      kl_r[0][ks] = *(const bf16x8*)(Kl + kro);
      ql_r[0][ks] = *(const bf16x8*)(Ql_g + qoff + ks * 32);
    }
    f32x4 S[8];
    int cur = 0;
#pragma unroll
    for (int h = 0; h < 8; ++h) {
      const int nxt = cur ^ 1;
      if (h < 7) {
#pragma unroll
        for (int ks = 0; ks < 2; ++ks) {
          size_t kro = (((size_t)(b * 8 + h + 1) * 1024 + jj) << 6) + ks * 32 + quad * 8;
          kh_r[nxt][ks] = *(const bf16x8*)(Kh + kro);
          kl_r[nxt][ks] = *(const bf16x8*)(Kl + kro);
          ql_r[nxt][ks] = *(const bf16x8*)(Ql_g + qoff + (size_t)(h + 1) * 65536 + ks * 32);
        }
      }
      f32x4 acc = zero4();
#pragma unroll
      for (int ks = 0; ks < 2; ++ks) {
        bf16x8 ah = *(const bf16x8*)&Qsh[(h * 16 + ln) * 72 + ks * 32 + quad * 8];
        acc = mfma16(ah, kh_r[cur][ks], acc);
        acc = mfma16(ah, kl_r[cur][ks], acc);
        acc = mfma16(ql_r[cur][ks], kh_r[cur][ks], acc);
      }
      S[h] = acc;
      cur = nxt;
    }
    const int dr = jj - ig0;
    f32x4 P[8];
#pragma unroll
    for (int a = 0; a < 8; ++a) {
      f32x4 sm = S[0] * mixp_s[a];
#pragma unroll
      for (int h = 1; h < 8; ++h) sm += S[h] * mixp_s[h * 8 + a];
      const float df = dfix_s[a];
      f32x4 il4 = *(const f32x4*)&Ils[a][quad * 4];
      f32x4 p;
#pragma unroll
      for (int r = 0; r < 4; ++r) {
        float vv = (r == dr) ? df : sm[r];
        p[r] = __expf(vv) * il4[r];
      }
      P[a] = p;
    }
    // ---- postmix -> Ws hi/lo ----
#pragma unroll
    for (int c = 0; c < 8; ++c) {
      f32x4 wv = P[0] * mixq_s[c];
#pragma unroll
      for (int a = 1; a < 8; ++a) wv += P[a] * mixq_s[a * 8 + c];
#pragma unroll
      for (int r = 0; r < 4; ++r) {
        unsigned short vhh, vll;
        splitbf(wv[r], vhh, vll);
        int o = (c * 16 + quad * 4 + r) * 72 + jh + ln;
        Wsh[o] = vhh; Wsl[o] = vll;
      }
    }
    __syncthreads();
    // ---- PV: 4 steps (cc,ks); V prefetch chained across steps and tiles
#pragma unroll
    for (int s = 0; s < 4; ++s) {
      const int cc = s >> 1, ks = s & 1;
      const int c = cw + cc;
      const int vcur = s & 1, vnxt = vcur ^ 1;
      if (s < 3) {
        const int cc2 = (s + 1) >> 1, ks2 = (s + 1) & 1;
#pragma unroll
        for (int nt = 0; nt < 4; ++nt) {
          size_t vo = (((size_t)(b * 8 + cw + cc2) * 64 + nt * 16 + ln) << 10) +
                      j0 + ks2 * 32 + quad * 8;
          vbh[vnxt][nt] = *(const bf16x8*)(Vh + vo);
          vbl[vnxt][nt] = *(const bf16x8*)(Vl + vo);
        }
      } else if (j0 < 960) {  // chain: next tile's step 0
#pragma unroll
        for (int nt = 0; nt < 4; ++nt) {
          size_t vo = (((size_t)(b * 8 + cw) * 64 + nt * 16 + ln) << 10) +
                      j0 + 64 + quad * 8;
          vbh[vnxt][nt] = *(const bf16x8*)(Vh + vo);
          vbl[vnxt][nt] = *(const bf16x8*)(Vl + vo);
        }
      }
      bf16x8 a_h = *(const bf16x8*)&Wsh[(c * 16 + ln) * 72 + ks * 32 + quad * 8];
      bf16x8 a_l = *(const bf16x8*)&Wsl[(c * 16 + ln) * 72 + ks * 32 + quad * 8];
#pragma unroll
      for (int nt = 0; nt < 4; ++nt) {
        O[cc][nt] = mfma16(a_h, vbh[vcur][nt], O[cc][nt]);
        O[cc][nt] = mfma16(a_h, vbl[vcur][nt], O[cc][nt]);
        O[cc][nt] = mfma16(a_l, vbh[vcur][nt], O[cc][nt]);
      }
    }
    __syncthreads();
  }
#pragma unroll
  for (int cc = 0; cc < 2; ++cc)
#pragma unroll
    for (int nt = 0; nt < 4; ++nt)
#pragma unroll
      for (int r = 0; r < 4; ++r) {
        const int i = i0 + quad * 4 + r;
        const int col = (cw + cc) * 64 + nt * 16 + ln;
        OA[((size_t)(b * 1024 + i) << 9) + col] = O[cc][nt][r];
      }
}

// ------------------------------------------------------------- P4: out-proj
__global__ __launch_bounds__(256) void gemm_out(
    const float* __restrict__ A, const unsigned short* __restrict__ BTh,
    const unsigned short* __restrict__ BTl, const float* __restrict__ bias,
    float* __restrict__ Out) {
  __shared__ unsigned short Ah[128 * 72], Al[128 * 72];
  __shared__ unsigned short Bh[128 * 72], Bl[128 * 72];
  const int tid = threadIdx.x;
  const int n0 = blockIdx.x * 128, m0 = blockIdx.y * 128;
  const int w = tid >> 6, lane = tid & 63, quad = lane >> 4, ln = lane & 15;
  const int mw = (w >> 1) * 64, nw = (w & 1) * 64;
  const int srow = tid >> 3, schk = (tid & 7) * 8;
  f32x4 acc[4][4];
#pragma unroll
  for (int i = 0; i < 4; ++i)
#pragma unroll
    for (int j = 0; j < 4; ++j) acc[i][j] = zero4();
  for (int k0 = 0; k0 < 512; k0 += 64) {
    float xa[4][8];
    uint4 bh4[4], bl4[4];
#pragma unroll
    for (int c2 = 0; c2 < 4; ++c2) {
      const float* xs = A + (size_t)(m0 + c2 * 32 + srow) * 512 + k0 + schk;
      *(float4*)&xa[c2][0] = *(const float4*)xs;
      *(float4*)&xa[c2][4] = *(const float4*)(xs + 4);
      size_t boff = (size_t)(n0 + c2 * 32 + srow) * 512 + k0 + schk;
      bh4[c2] = *(const uint4*)(BTh + boff);
      bl4[c2] = *(const uint4*)(BTl + boff);
    }
    __syncthreads();
#pragma unroll
    for (int c2 = 0; c2 < 4; ++c2) {
      unsigned short hh[8], ll[8];
#pragma unroll
      for (int e = 0; e < 8; ++e) splitbf(xa[c2][e], hh[e], ll[e]);
      uint4 ph, pl;
      ph.x = hh[0] | ((unsigned)hh[1] << 16); pl.x = ll[0] | ((unsigned)ll[1] << 16);
      ph.y = hh[2] | ((unsigned)hh[3] << 16); pl.y = ll[2] | ((unsigned)ll[3] << 16);
      ph.z = hh[4] | ((unsigned)hh[5] << 16); pl.z = ll[4] | ((unsigned)ll[5] << 16);
      ph.w = hh[6] | ((unsigned)hh[7] << 16); pl.w = ll[6] | ((unsigned)ll[7] << 16);
      *(uint4*)&Ah[(c2 * 32 + srow) * 72 + schk] = ph;
      *(uint4*)&Al[(c2 * 32 + srow) * 72 + schk] = pl;
      *(uint4*)&Bh[(c2 * 32 + srow) * 72 + schk] = bh4[c2];
      *(uint4*)&Bl[(c2 * 32 + srow) * 72 + schk] = bl4[c2];
    }
    __syncthreads();
#pragma unroll
    for (int ks = 0; ks < 2; ++ks) {
      bf16x8 afh[4], afl[4], bfh[4], bfl[4];
#pragma unroll
      for (int t = 0; t < 4; ++t) {
        int ao = (mw + t * 16 + ln) * 72 + ks * 32 + quad * 8;
        int bo = (nw + t * 16 + ln) * 72 + ks * 32 + quad * 8;
        afh[t] = *(const bf16x8*)&Ah[ao];
        afl[t] = *(const bf16x8*)&Al[ao];
        bfh[t] = *(const bf16x8*)&Bh[bo];
        bfl[t] = *(const bf16x8*)&Bl[bo];
      }
#pragma unroll
      for (int mt = 0; mt < 4; ++mt)
#pragma unroll
        for (int nt = 0; nt < 4; ++nt) {
          acc[mt][nt] = mfma16(afh[mt], bfh[nt], acc[mt][nt]);
          acc[mt][nt] = mfma16(afh[mt], bfl[nt], acc[mt][nt]);
          acc[mt][nt] = mfma16(afl[mt], bfh[nt], acc[mt][nt]);
        }
    }
  }
#pragma unroll
  for (int nt = 0; nt < 4; ++nt) {
    const int col = n0 + nw + nt * 16 + ln;
    const float bcol = bias[col];
#pragma unroll
    for (int mt = 0; mt < 4; ++mt) {
#pragma unroll
      for (int r = 0; r < 4; ++r) {
        const int row = m0 + mw + mt * 16 + quad * 4 + r;
        Out[(size_t)row * 512 + col] = acc[mt][nt][r] + bcol;
      }
    }
  }
}

}  // namespace

extern "C" void kernel_launch(void* const* d_in, const int* in_sizes, int n_in,
                              void* d_out, int out_size, void* d_ws, size_t ws_size,
                              hipStream_t stream) {
  const float* x        = (const float*)d_in[0];
  const float* Wq       = (const float*)d_in[1];
  const float* Wkv      = (const float*)d_in[2];
  const float* scale    = (const float*)d_in[3];
  const float* mix_pre  = (const float*)d_in[4];
  const float* mix_post = (const float*)d_in[5];
  const float* Wout     = (const float*)d_in[6];
  const float* bout     = (const float*)d_in[7];
  float* out = (float*)d_out;

  char* p = (char*)d_ws;
  const size_t qsz = (size_t)kB * kH * kN * 64;  // 8,388,608 elems
  unsigned short* WTh  = (unsigned short*)p; p += (size_t)1536 * 512 * 2;
  unsigned short* WTl  = (unsigned short*)p; p += (size_t)1536 * 512 * 2;
  unsigned short* WoTh = (unsigned short*)p; p += (size_t)512 * 512 * 2;
  unsigned short* WoTl = (unsigned short*)p; p += (size_t)512 * 512 * 2;
  unsigned short* Qh   = (unsigned short*)p; p += qsz * 2;
  unsigned short* Ql   = (unsigned short*)p; p += qsz * 2;
  unsigned short* Kh   = (unsigned short*)p; p += qsz * 2;
  unsigned short* Kl   = (unsigned short*)p; p += qsz * 2;
  unsigned short* Vh   = (unsigned short*)p; p += qsz * 2;
  unsigned short* Vl   = (unsigned short*)p; p += qsz * 2;
  float* OA = (float*)p; p += (size_t)kB * kN * 512 * 4;  // fp32, 33.5 MB
  float* ILp = (float*)p; p += (size_t)131072 * 4;        // 0.5 MB
  // total fixed ~139 MB (same as the known-good fused config)

  prep<<<4096, 256, 0, stream>>>(Wq, Wkv, Wout, WTh, WTl, WoTh, WoTl);
  gemm_qkv<<<dim3(12, 128), 256, 0, stream>>>(x, WTh, WTl, scale,
                                              Qh, Ql, Kh, Kl, Vh, Vl);
  attn_lsum<<<dim3(64, 16), 256, 0, stream>>>(Qh, Ql, Kh, Kl, mix_pre, ILp);
  attn_pv<<<dim3(64, 16), 256, 0, stream>>>(Qh, Ql, Kh, Kl, Vh, Vl, ILp,
                                            mix_pre, mix_post, OA);
  gemm_out<<<dim3(4, 128), 256, 0, stream>>>(OA, WoTh, WoTl, bout, out);
}

// Round 9
// 1507.785 us; speedup vs baseline: 1.2688x; 1.0474x over previous
//
#include <hip/hip_runtime.h>
#include <math.h>

// ---------------------------------------------------------------------------
// bf16 MFMA with two-term hi/lo splits for fp32-grade accuracy.
// a*b ~= ah*bh + ah*bl + al*bh (lo*lo dropped). All MFMA accumulation fp32.
// Frag layouts (HW-verified): A/B: m|n = lane&15, k = (lane>>4)*8 + t;
// C/D: col = lane&15, row = (lane>>4)*4 + reg.
//
// Round-9: round-8's one-pass attn was ALGEBRAICALLY WRONG (attention
// weights of head a pair with V of OUTPUT head g, not V[a]; avoiding
// in-loop postmix needs 64 (a,g) pairs = 8x PV). Revert to the proven
// round-7 two-pass attn:
//   attn_lsum: QK^T + premix + exp -> l -> IL = 1/l. NOW 2-term QK^T
//              (QhKh + QhKl; dropping QlKh adds ~1e-5 rel error on l,
//              ~5e-6 abs on out) and no Ql loads at all.
//   attn_pv:   recompute S (exact 3-term), p = exp(s)*IL, postmix -> W
//              hi/lo LDS, PV vs V with chained V prefetch.
// KEEP round-8's gemm_qkv V-transpose epilogue (verified mapping, never
// timed): V region stages the 128x128 tile in LDS and stores uint4 runs
// along i -> fixes WRITE_SIZE 505 MB -> ~120 MB (was fill-BW bound).
// ---------------------------------------------------------------------------

typedef short bf16x8 __attribute__((ext_vector_type(8)));
typedef float f32x4 __attribute__((ext_vector_type(4)));

__device__ __forceinline__ f32x4 mfma16(bf16x8 a, bf16x8 b, f32x4 c) {
  return __builtin_amdgcn_mfma_f32_16x16x32_bf16(a, b, c, 0, 0, 0);
}

__device__ __forceinline__ unsigned short f2bf(float f) {
  unsigned u = __float_as_uint(f);
  u = (u + 0x7fffu + ((u >> 16) & 1u)) >> 16;  // RNE
  return (unsigned short)u;
}

__device__ __forceinline__ void splitbf(float f, unsigned short& hi,
                                        unsigned short& lo) {
  hi = f2bf(f);
  float fh = __uint_as_float((unsigned)hi << 16);
  lo = f2bf(f - fh);
}

__device__ __forceinline__ f32x4 zero4() {
  f32x4 z = {0.f, 0.f, 0.f, 0.f};
  return z;
}

namespace {

constexpr int kB = 16, kN = 1024, kH = 8;

// ------------------------------------------------------------------ P0: prep
__global__ __launch_bounds__(256) void prep(
    const float* __restrict__ Wq, const float* __restrict__ Wkv,
    const float* __restrict__ Wout, unsigned short* __restrict__ WTh,
    unsigned short* __restrict__ WTl, unsigned short* __restrict__ WoTh,
    unsigned short* __restrict__ WoTl) {
  int id = blockIdx.x * 256 + threadIdx.x;  // 1,048,576 ids
  unsigned short h, l;
  if (id < 1536 * 512) {
    int n = id >> 9, k = id & 511;
    float v = (n < 512) ? Wq[(size_t)k * 512 + n]
                        : Wkv[(size_t)k * 1024 + (n - 512)];
    splitbf(v, h, l);
    WTh[id] = h; WTl[id] = l;
  } else {
    int id2 = id - 1536 * 512;
    int n = id2 >> 9, k = id2 & 511;
    splitbf(Wout[(size_t)k * 512 + n], h, l);
    WoTh[id2] = h; WoTl[id2] = l;
  }
}

// ----------------------------------------------------------------- P1: QKV
__global__ __launch_bounds__(256) void gemm_qkv(
    const float* __restrict__ X, const unsigned short* __restrict__ WTh,
    const unsigned short* __restrict__ WTl, const float* __restrict__ scale,
    unsigned short* __restrict__ Qh, unsigned short* __restrict__ Ql,
    unsigned short* __restrict__ Kh, unsigned short* __restrict__ Kl,
    unsigned short* __restrict__ Vh, unsigned short* __restrict__ Vl) {
  __shared__ __align__(16) char gblob[4 * 128 * 72 * 2];  // 73728 B
  unsigned short* Ah = (unsigned short*)gblob;
  unsigned short* Al = Ah + 128 * 72;
  unsigned short* Bh = Al + 128 * 72;
  unsigned short* Bl = Bh + 128 * 72;
  const int tid = threadIdx.x;
  const int n0 = blockIdx.x * 128, m0 = blockIdx.y * 128;
  const int w = tid >> 6, lane = tid & 63, quad = lane >> 4, ln = lane & 15;
  const int mw = (w >> 1) * 64, nw = (w & 1) * 64;
  const int srow = tid >> 3, schk = (tid & 7) * 8;
  f32x4 acc[4][4];
#pragma unroll
  for (int i = 0; i < 4; ++i)
#pragma unroll
    for (int j = 0; j < 4; ++j) acc[i][j] = zero4();
  for (int k0 = 0; k0 < 512; k0 += 64) {
    float xa[4][8];
    uint4 bh4[4], bl4[4];
#pragma unroll
    for (int c2 = 0; c2 < 4; ++c2) {
      const float* xs = X + (size_t)(m0 + c2 * 32 + srow) * 512 + k0 + schk;
      *(float4*)&xa[c2][0] = *(const float4*)xs;
      *(float4*)&xa[c2][4] = *(const float4*)(xs + 4);
      size_t boff = (size_t)(n0 + c2 * 32 + srow) * 512 + k0 + schk;
      bh4[c2] = *(const uint4*)(WTh + boff);
      bl4[c2] = *(const uint4*)(WTl + boff);
    }
    __syncthreads();
#pragma unroll
    for (int c2 = 0; c2 < 4; ++c2) {
      unsigned short hh[8], ll[8];
#pragma unroll
      for (int e = 0; e < 8; ++e) splitbf(xa[c2][e], hh[e], ll[e]);
      uint4 ph, pl;
      ph.x = hh[0] | ((unsigned)hh[1] << 16); pl.x = ll[0] | ((unsigned)ll[1] << 16);
      ph.y = hh[2] | ((unsigned)hh[3] << 16); pl.y = ll[2] | ((unsigned)ll[3] << 16);
      ph.z = hh[4] | ((unsigned)hh[5] << 16); pl.z = ll[4] | ((unsigned)ll[5] << 16);
      ph.w = hh[6] | ((unsigned)hh[7] << 16); pl.w = ll[6] | ((unsigned)ll[7] << 16);
      *(uint4*)&Ah[(c2 * 32 + srow) * 72 + schk] = ph;
      *(uint4*)&Al[(c2 * 32 + srow) * 72 + schk] = pl;
      *(uint4*)&Bh[(c2 * 32 + srow) * 72 + schk] = bh4[c2];
      *(uint4*)&Bl[(c2 * 32 + srow) * 72 + schk] = bl4[c2];
    }
    __syncthreads();
#pragma unroll
    for (int ks = 0; ks < 2; ++ks) {
      bf16x8 afh[4], afl[4], bfh[4], bfl[4];
#pragma unroll
      for (int t = 0; t < 4; ++t) {
        int ao = (mw + t * 16 + ln) * 72 + ks * 32 + quad * 8;
        int bo = (nw + t * 16 + ln) * 72 + ks * 32 + quad * 8;
        afh[t] = *(const bf16x8*)&Ah[ao];
        afl[t] = *(const bf16x8*)&Al[ao];
        bfh[t] = *(const bf16x8*)&Bh[bo];
        bfl[t] = *(const bf16x8*)&Bl[bo];
      }
#pragma unroll
      for (int mt = 0; mt < 4; ++mt)
#pragma unroll
        for (int nt = 0; nt < 4; ++nt) {
          acc[mt][nt] = mfma16(afh[mt], bfh[nt], acc[mt][nt]);
          acc[mt][nt] = mfma16(afh[mt], bfl[nt], acc[mt][nt]);
          acc[mt][nt] = mfma16(afl[mt], bfh[nt], acc[mt][nt]);
        }
    }
  }
  const int region = n0 >> 9;
  if (region < 2) {
    // Q / K: d-contiguous layout; 4 nt-stores fill a 128B line per (i,head).
#pragma unroll
    for (int nt = 0; nt < 4; ++nt) {
      const int col = n0 + nw + nt * 16 + ln;
      const int local = col - region * 512;
      const int hh = local >> 6, d = local & 63;
      const float sc = (region == 0) ? scale[hh] : 1.f;
#pragma unroll
      for (int mt = 0; mt < 4; ++mt) {
#pragma unroll
        for (int r = 0; r < 4; ++r) {
          const int row = m0 + mw + mt * 16 + quad * 4 + r;
          const int b = row >> 10, i = row & 1023;
          unsigned short vh, vl;
          splitbf(acc[mt][nt][r] * sc, vh, vl);
          size_t o = (((size_t)(b * 8 + hh) * 1024 + i) << 6) + d;
          if (region == 0) { Qh[o] = vh; Ql[o] = vl; }
          else             { Kh[o] = vh; Kl[o] = vl; }
        }
      }
    }
  } else {
    // V: i-major target layout -> transpose via LDS, store uint4 along i.
    __syncthreads();  // staging buffers now dead; reuse as [128][132] hi/lo
    unsigned short* Th = (unsigned short*)gblob;       // 128*132 shorts
    unsigned short* Tl = Th + 128 * 132;               // total 67584 B
#pragma unroll
    for (int nt = 0; nt < 4; ++nt) {
      const int coll = nw + nt * 16 + ln;
#pragma unroll
      for (int mt = 0; mt < 4; ++mt) {
#pragma unroll
        for (int r = 0; r < 4; ++r) {
          const int mrow = mw + mt * 16 + quad * 4 + r;
          unsigned short vh, vl;
          splitbf(acc[mt][nt][r], vh, vl);
          Th[mrow * 132 + coll] = vh;
          Tl[mrow * 132 + coll] = vl;
        }
      }
    }
    __syncthreads();
    const int b = m0 >> 10, ibase = m0 & 1023;
#pragma unroll
    for (int k = 0; k < 8; ++k) {
      const int chunk = tid + 256 * k;       // 0..2047
      const int coll = chunk >> 4;           // 0..127
      const int ii8 = (chunk & 15) * 8;      // 0..120
      const int local512 = (n0 - 1024) + coll;
      const int hh = local512 >> 6, d = local512 & 63;
      unsigned short h8[8], l8[8];
#pragma unroll
      for (int e = 0; e < 8; ++e) {
        h8[e] = Th[(ii8 + e) * 132 + coll];
        l8[e] = Tl[(ii8 + e) * 132 + coll];
      }
      uint4 ph, pl;
      ph.x = h8[0] | ((unsigned)h8[1] << 16); pl.x = l8[0] | ((unsigned)l8[1] << 16);
      ph.y = h8[2] | ((unsigned)h8[3] << 16); pl.y = l8[2] | ((unsigned)l8[3] << 16);
      ph.z = h8[4] | ((unsigned)h8[5] << 16); pl.z = l8[4] | ((unsigned)l8[5] << 16);
      ph.w = h8[6] | ((unsigned)h8[7] << 16); pl.w = l8[6] | ((unsigned)l8[7] << 16);
      size_t o = (((size_t)(b * 8 + hh) * 64 + d) << 10) + ibase + ii8;
      *(uint4*)(Vh + o) = ph;
      *(uint4*)(Vl + o) = pl;
    }
  }
}

// ------------------------------------------------------ P2a: l sums -> IL
// 256 threads = 4 waves, each wave owns a 16-j slice of a 16i x 64j tile.
// Barrier-free j-loop. 2-term QK^T (QhKh + QhKl): l tolerates ~1e-4 rel
// error; dropping QlKh (~2e-4 rel per logit, random-sign over j) gives
// dl/l ~ 1e-5. No Ql loads at all.
__global__ __launch_bounds__(256) void attn_lsum(
    const unsigned short* __restrict__ Qh_g,
    const unsigned short* __restrict__ Kh, const unsigned short* __restrict__ Kl,
    const float* __restrict__ mix_pre, float* __restrict__ IL) {
  __shared__ unsigned short Qsh[128 * 72];  // [8h*16i][72] hi
  __shared__ float mixp_s[64], dfix_s[8];
  __shared__ float lred[512];  // [4w][8a][16i]
  const int tid = threadIdx.x;
  const int b = blockIdx.y, ib = blockIdx.x, i0 = ib * 16;
  const int w = tid >> 6, lane = tid & 63, quad = lane >> 4, ln = lane & 15;
  const int jh = w * 16;
  if (tid < 64) mixp_s[tid] = mix_pre[tid];
  if (tid < 8) {
    float s = 0.f;
#pragma unroll
    for (int h = 0; h < 8; ++h) s += mix_pre[h * 8 + tid];
    dfix_s[tid] = -1e-9f * s;  // diagonal is assigned BEFORE premix
  }
  // stage Q-hi: 8h*16i*64d shorts = 1024 uint4 chunks / 256 threads
#pragma unroll
  for (int c = 0; c < 4; ++c) {
    int v = tid + 256 * c;
    int row = v >> 3, chk = (v & 7) * 8;  // row = h*16 + i
    int h = row >> 4, ii = row & 15;
    *(uint4*)&Qsh[row * 72 + chk] =
        *(const uint4*)(Qh_g + (((size_t)(b * 8 + h) * 1024 + i0 + ii) << 6) + chk);
  }
  __syncthreads();
  const int ig0 = i0 + quad * 4;
  float l[8][4];
#pragma unroll
  for (int a = 0; a < 8; ++a)
#pragma unroll
    for (int r = 0; r < 4; ++r) l[a][r] = 0.f;
#pragma unroll 1
  for (int j0 = 0; j0 < 1024; j0 += 64) {
    const int jj = j0 + jh + ln;  // this lane's j (B-frag n-index)
    bf16x8 kh_r[2][2], kl_r[2][2];
#pragma unroll
    for (int ks = 0; ks < 2; ++ks) {
      size_t kro = (((size_t)(b * 8) * 1024 + jj) << 6) + ks * 32 + quad * 8;
      kh_r[0][ks] = *(const bf16x8*)(Kh + kro);
      kl_r[0][ks] = *(const bf16x8*)(Kl + kro);
    }
    f32x4 S[8];
    int cur = 0;
#pragma unroll
    for (int h = 0; h < 8; ++h) {
      const int nxt = cur ^ 1;
      if (h < 7) {
#pragma unroll
        for (int ks = 0; ks < 2; ++ks) {
          size_t kro = (((size_t)(b * 8 + h + 1) * 1024 + jj) << 6) + ks * 32 + quad * 8;
          kh_r[nxt][ks] = *(const bf16x8*)(Kh + kro);
          kl_r[nxt][ks] = *(const bf16x8*)(Kl + kro);
        }
      }
      f32x4 acc = zero4();
#pragma unroll
      for (int ks = 0; ks < 2; ++ks) {
        bf16x8 ah = *(const bf16x8*)&Qsh[(h * 16 + ln) * 72 + ks * 32 + quad * 8];
        acc = mfma16(ah, kh_r[cur][ks], acc);
        acc = mfma16(ah, kl_r[cur][ks], acc);
      }
      S[h] = acc;
      cur = nxt;
    }
    const int dr = jj - ig0;
#pragma unroll
    for (int a = 0; a < 8; ++a) {
      f32x4 sm = S[0] * mixp_s[a];
#pragma unroll
      for (int h = 1; h < 8; ++h) sm += S[h] * mixp_s[h * 8 + a];
      const float df = dfix_s[a];
#pragma unroll
      for (int r = 0; r < 4; ++r) {
        float vv = (r == dr) ? df : sm[r];
        l[a][r] += __expf(vv);
      }
    }
  }
  // reduce l over ln (16 lanes), then over 4 waves via LDS
#pragma unroll
  for (int off = 1; off < 16; off <<= 1)
#pragma unroll
    for (int a = 0; a < 8; ++a)
#pragma unroll
      for (int r = 0; r < 4; ++r) l[a][r] += __shfl_xor(l[a][r], off);
  if (ln == 0) {
#pragma unroll
    for (int a = 0; a < 8; ++a)
#pragma unroll
      for (int r = 0; r < 4; ++r)
        lred[(w * 8 + a) * 16 + quad * 4 + r] = l[a][r];
  }
  __syncthreads();
  if (tid < 128) {
    int a = tid >> 4, i = tid & 15;
    float s = lred[a * 16 + i] + lred[(8 + a) * 16 + i] +
              lred[(16 + a) * 16 + i] + lred[(24 + a) * 16 + i];
    IL[(((size_t)b * 8 + a) << 10) + i0 + i] = 1.f / s;
  }
}

// --------------------------------- P2b: recompute S, postmix, PV (exact)
__global__ __launch_bounds__(256) void attn_pv(
    const unsigned short* __restrict__ Qh_g, const unsigned short* __restrict__ Ql_g,
    const unsigned short* __restrict__ Kh, const unsigned short* __restrict__ Kl,
    const unsigned short* __restrict__ Vh, const unsigned short* __restrict__ Vl,
    const float* __restrict__ IL, const float* __restrict__ mix_pre,
    const float* __restrict__ mix_post, float* __restrict__ OA) {
  __shared__ unsigned short Qsh[128 * 72];                 // [8h*16i][72] hi
  __shared__ unsigned short Wsh[128 * 72], Wsl[128 * 72];  // [8c*16i][72]
  __shared__ float mixp_s[64], mixq_s[64], dfix_s[8];
  __shared__ float Ils[8][16];
  const int tid = threadIdx.x;
  const int b = blockIdx.y, ib = blockIdx.x, i0 = ib * 16;
  const int w = tid >> 6, lane = tid & 63, quad = lane >> 4, ln = lane & 15;
  const int jh = w * 16;
  if (tid < 64) { mixp_s[tid] = mix_pre[tid]; mixq_s[tid] = mix_post[tid]; }
  if (tid < 8) {
    float s = 0.f;
#pragma unroll
    for (int h = 0; h < 8; ++h) s += mix_pre[h * 8 + tid];
    dfix_s[tid] = -1e-9f * s;
  }
  if (tid >= 128) {
    int a = (tid - 128) >> 4, i = tid & 15;
    Ils[a][i] = IL[(((size_t)b * 8 + a) << 10) + i0 + i];
  }
  // stage Q-hi
#pragma unroll
  for (int c = 0; c < 4; ++c) {
    int v = tid + 256 * c;
    int row = v >> 3, chk = (v & 7) * 8;
    int h = row >> 4, ii = row & 15;
    *(uint4*)&Qsh[row * 72 + chk] =
        *(const uint4*)(Qh_g + (((size_t)(b * 8 + h) * 1024 + i0 + ii) << 6) + chk);
  }
  __syncthreads();
  const int ig0 = i0 + quad * 4;
  const int cw = w * 2;
  const size_t qoff = (((size_t)(b * 8) * 1024 + i0 + ln) << 6) + quad * 8;
  f32x4 O[2][4];
#pragma unroll
  for (int cc = 0; cc < 2; ++cc)
#pragma unroll
    for (int nt = 0; nt < 4; ++nt) O[cc][nt] = zero4();
  // prologue: V frags for tile 0, step 0 (c=cw, ks=0)
  bf16x8 vbh[2][4], vbl[2][4];
#pragma unroll
  for (int nt = 0; nt < 4; ++nt) {
    size_t vo = (((size_t)(b * 8 + cw) * 64 + nt * 16 + ln) << 10) + quad * 8;
    vbh[0][nt] = *(const bf16x8*)(Vh + vo);
    vbl[0][nt] = *(const bf16x8*)(Vl + vo);
  }
#pragma unroll 1
  for (int j0 = 0; j0 < 1024; j0 += 64) {
    const int jj = j0 + jh + ln;
    // ---- S phase (exact 3-term) ----
    bf16x8 kh_r[2][2], kl_r[2][2], ql_r[2][2];
#pragma unroll
    for (int ks = 0; ks < 2; ++ks) {
      size_t kro = (((size_t)(b * 8) * 1024 + jj) << 6) + ks * 32 + quad * 8;
      kh_r[0][ks] = *(const bf16x8*)(Kh + kro);
      kl_r[0][ks] = *(const bf16x8*)(Kl + kro);
      ql_r[0][ks] = *(const bf16x8*)(Ql_g + qoff + ks * 32);
    }
    f32x4 S[8];
    int cur = 0;
#pragma unroll
    for (int h = 0; h < 8; ++h) {
      const int nxt = cur ^ 1;
      if (h < 7) {
#pragma unroll
        for (int ks = 0; ks < 2; ++ks) {
          size_t kro = (((size_t)(b * 8 + h + 1) * 1024 + jj) << 6) + ks * 32 + quad * 8;
          kh_r[nxt][ks] = *(const bf16x8*)(Kh + kro);
          kl_r[nxt][ks] = *(const bf16x8*)(Kl + kro);
          ql_r[nxt][ks] = *(const bf16x8*)(Ql_g + qoff + (size_t)(h + 1) * 65536 + ks * 32);
        }
      }
      f32x4 acc = zero4();
#pragma unroll
      for (int ks = 0; ks < 2; ++ks) {
        bf16x8 ah = *(const bf16x8*)&Qsh[(h * 16 + ln) * 72 + ks * 32 + quad * 8];
        acc = mfma16(ah, kh_r[cur][ks], acc);
        acc = mfma16(ah, kl_r[cur][ks], acc);
        acc = mfma16(ql_r[cur][ks], kh_r[cur][ks], acc);
      }
      S[h] = acc;
      cur = nxt;
    }
    const int dr = jj - ig0;
    f32x4 P[8];
#pragma unroll
    for (int a = 0; a < 8; ++a) {
      f32x4 sm = S[0] * mixp_s[a];
#pragma unroll
      for (int h = 1; h < 8; ++h) sm += S[h] * mixp_s[h * 8 + a];
      const float df = dfix_s[a];
      f32x4 il4 = *(const f32x4*)&Ils[a][quad * 4];
      f32x4 p;
#pragma unroll
      for (int r = 0; r < 4; ++r) {
        float vv = (r == dr) ? df : sm[r];
        p[r] = __expf(vv) * il4[r];
      }
      P[a] = p;
    }
    // ---- postmix -> Ws hi/lo ----
#pragma unroll
    for (int c = 0; c < 8; ++c) {
      f32x4 wv = P[0] * mixq_s[c];
#pragma unroll
      for (int a = 1; a < 8; ++a) wv += P[a] * mixq_s[a * 8 + c];
#pragma unroll
      for (int r = 0; r < 4; ++r) {
        unsigned short vhh, vll;
        splitbf(wv[r], vhh, vll);
        int o = (c * 16 + quad * 4 + r) * 72 + jh + ln;
        Wsh[o] = vhh; Wsl[o] = vll;
      }
    }
    __syncthreads();
    // ---- PV: 4 steps (cc,ks); V prefetch chained across steps and tiles
#pragma unroll
    for (int s = 0; s < 4; ++s) {
      const int cc = s >> 1, ks = s & 1;
      const int c = cw + cc;
      const int vcur = s & 1, vnxt = vcur ^ 1;
      if (s < 3) {
        const int cc2 = (s + 1) >> 1, ks2 = (s + 1) & 1;
#pragma unroll
        for (int nt = 0; nt < 4; ++nt) {
          size_t vo = (((size_t)(b * 8 + cw + cc2) * 64 + nt * 16 + ln) << 10) +
                      j0 + ks2 * 32 + quad * 8;
          vbh[vnxt][nt] = *(const bf16x8*)(Vh + vo);
          vbl[vnxt][nt] = *(const bf16x8*)(Vl + vo);
        }
      } else if (j0 < 960) {  // chain: next tile's step 0
#pragma unroll
        for (int nt = 0; nt < 4; ++nt) {
          size_t vo = (((size_t)(b * 8 + cw) * 64 + nt * 16 + ln) << 10) +
                      j0 + 64 + quad * 8;
          vbh[vnxt][nt] = *(const bf16x8*)(Vh + vo);
          vbl[vnxt][nt] = *(const bf16x8*)(Vl + vo);
        }
      }
      bf16x8 a_h = *(const bf16x8*)&Wsh[(c * 16 + ln) * 72 + ks * 32 + quad * 8];
      bf16x8 a_l = *(const bf16x8*)&Wsl[(c * 16 + ln) * 72 + ks * 32 + quad * 8];
#pragma unroll
      for (int nt = 0; nt < 4; ++nt) {
        O[cc][nt] = mfma16(a_h, vbh[vcur][nt], O[cc][nt]);
        O[cc][nt] = mfma16(a_h, vbl[vcur][nt], O[cc][nt]);
        O[cc][nt] = mfma16(a_l, vbh[vcur][nt], O[cc][nt]);
      }
    }
    __syncthreads();
  }
#pragma unroll
  for (int cc = 0; cc < 2; ++cc)
#pragma unroll
    for (int nt = 0; nt < 4; ++nt)
#pragma unroll
      for (int r = 0; r < 4; ++r) {
        const int i = i0 + quad * 4 + r;
        const int col = (cw + cc) * 64 + nt * 16 + ln;
        OA[((size_t)(b * 1024 + i) << 9) + col] = O[cc][nt][r];
      }
}

// ------------------------------------------------------------- P4: out-proj
__global__ __launch_bounds__(256) void gemm_out(
    const float* __restrict__ A, const unsigned short* __restrict__ BTh,
    const unsigned short* __restrict__ BTl, const float* __restrict__ bias,
    float* __restrict__ Out) {
  __shared__ unsigned short Ah[128 * 72], Al[128 * 72];
  __shared__ unsigned short Bh[128 * 72], Bl[128 * 72];
  const int tid = threadIdx.x;
  const int n0 = blockIdx.x * 128, m0 = blockIdx.y * 128;
  const int w = tid >> 6, lane = tid & 63, quad = lane >> 4, ln = lane & 15;
  const int mw = (w >> 1) * 64, nw = (w & 1) * 64;
  const int srow = tid >> 3, schk = (tid & 7) * 8;
  f32x4 acc[4][4];
#pragma unroll
  for (int i = 0; i < 4; ++i)
#pragma unroll
    for (int j = 0; j < 4; ++j) acc[i][j] = zero4();
  for (int k0 = 0; k0 < 512; k0 += 64) {
    float xa[4][8];
    uint4 bh4[4], bl4[4];
#pragma unroll
    for (int c2 = 0; c2 < 4; ++c2) {
      const float* xs = A + (size_t)(m0 + c2 * 32 + srow) * 512 + k0 + schk;
      *(float4*)&xa[c2][0] = *(const float4*)xs;
      *(float4*)&xa[c2][4] = *(const float4*)(xs + 4);
      size_t boff = (size_t)(n0 + c2 * 32 + srow) * 512 + k0 + schk;
      bh4[c2] = *(const uint4*)(BTh + boff);
      bl4[c2] = *(const uint4*)(BTl + boff);
    }
    __syncthreads();
#pragma unroll
    for (int c2 = 0; c2 < 4; ++c2) {
      unsigned short hh[8], ll[8];
#pragma unroll
      for (int e = 0; e < 8; ++e) splitbf(xa[c2][e], hh[e], ll[e]);
      uint4 ph, pl;
      ph.x = hh[0] | ((unsigned)hh[1] << 16); pl.x = ll[0] | ((unsigned)ll[1] << 16);
      ph.y = hh[2] | ((unsigned)hh[3] << 16); pl.y = ll[2] | ((unsigned)ll[3] << 16);
      ph.z = hh[4] | ((unsigned)hh[5] << 16); pl.z = ll[4] | ((unsigned)ll[5] << 16);
      ph.w = hh[6] | ((unsigned)hh[7] << 16); pl.w = ll[6] | ((unsigned)ll[7] << 16);
      *(uint4*)&Ah[(c2 * 32 + srow) * 72 + schk] = ph;
      *(uint4*)&Al[(c2 * 32 + srow) * 72 + schk] = pl;
      *(uint4*)&Bh[(c2 * 32 + srow) * 72 + schk] = bh4[c2];
      *(uint4*)&Bl[(c2 * 32 + srow) * 72 + schk] = bl4[c2];
    }
    __syncthreads();
#pragma unroll
    for (int ks = 0; ks < 2; ++ks) {
      bf16x8 afh[4], afl[4], bfh[4], bfl[4];
#pragma unroll
      for (int t = 0; t < 4; ++t) {
        int ao = (mw + t * 16 + ln) * 72 + ks * 32 + quad * 8;
        int bo = (nw + t * 16 + ln) * 72 + ks * 32 + quad * 8;
        afh[t] = *(const bf16x8*)&Ah[ao];
        afl[t] = *(const bf16x8*)&Al[ao];
        bfh[t] = *(const bf16x8*)&Bh[bo];
        bfl[t] = *(const bf16x8*)&Bl[bo];
      }
#pragma unroll
      for (int mt = 0; mt < 4; ++mt)
#pragma unroll
        for (int nt = 0; nt < 4; ++nt) {
          acc[mt][nt] = mfma16(afh[mt], bfh[nt], acc[mt][nt]);
          acc[mt][nt] = mfma16(afh[mt], bfl[nt], acc[mt][nt]);
          acc[mt][nt] = mfma16(afl[mt], bfh[nt], acc[mt][nt]);
        }
    }
  }
#pragma unroll
  for (int nt = 0; nt < 4; ++nt) {
    const int col = n0 + nw + nt * 16 + ln;
    const float bcol = bias[col];
#pragma unroll
    for (int mt = 0; mt < 4; ++mt) {
#pragma unroll
      for (int r = 0; r < 4; ++r) {
        const int row = m0 + mw + mt * 16 + quad * 4 + r;
        Out[(size_t)row * 512 + col] = acc[mt][nt][r] + bcol;
      }
    }
  }
}

}  // namespace

extern "C" void kernel_launch(void* const* d_in, const int* in_sizes, int n_in,
                              void* d_out, int out_size, void* d_ws, size_t ws_size,
                              hipStream_t stream) {
  const float* x        = (const float*)d_in[0];
  const float* Wq       = (const float*)d_in[1];
  const float* Wkv      = (const float*)d_in[2];
  const float* scale    = (const float*)d_in[3];
  const float* mix_pre  = (const float*)d_in[4];
  const float* mix_post = (const float*)d_in[5];
  const float* Wout     = (const float*)d_in[6];
  const float* bout     = (const float*)d_in[7];
  float* out = (float*)d_out;

  char* p = (char*)d_ws;
  const size_t qsz = (size_t)kB * kH * kN * 64;  // 8,388,608 elems
  unsigned short* WTh  = (unsigned short*)p; p += (size_t)1536 * 512 * 2;
  unsigned short* WTl  = (unsigned short*)p; p += (size_t)1536 * 512 * 2;
  unsigned short* WoTh = (unsigned short*)p; p += (size_t)512 * 512 * 2;
  unsigned short* WoTl = (unsigned short*)p; p += (size_t)512 * 512 * 2;
  unsigned short* Qh   = (unsigned short*)p; p += qsz * 2;
  unsigned short* Ql   = (unsigned short*)p; p += qsz * 2;
  unsigned short* Kh   = (unsigned short*)p; p += qsz * 2;
  unsigned short* Kl   = (unsigned short*)p; p += qsz * 2;
  unsigned short* Vh   = (unsigned short*)p; p += qsz * 2;
  unsigned short* Vl   = (unsigned short*)p; p += qsz * 2;
  float* OA = (float*)p; p += (size_t)kB * kN * 512 * 4;  // fp32, 33.5 MB
  float* ILp = (float*)p; p += (size_t)131072 * 4;        // 0.5 MB
  // total fixed ~139 MB (known to fit)

  prep<<<4096, 256, 0, stream>>>(Wq, Wkv, Wout, WTh, WTl, WoTh, WoTl);
  gemm_qkv<<<dim3(12, 128), 256, 0, stream>>>(x, WTh, WTl, scale,
                                              Qh, Ql, Kh, Kl, Vh, Vl);
  attn_lsum<<<dim3(64, 16), 256, 0, stream>>>(Qh, Kh, Kl, mix_pre, ILp);
  attn_pv<<<dim3(64, 16), 256, 0, stream>>>(Qh, Ql, Kh, Kl, Vh, Vl, ILp,
                                            mix_pre, mix_post, OA);
  gemm_out<<<dim3(4, 128), 256, 0, stream>>>(OA, WoTh, WoTl, bout, out);
}